// Round 7
// baseline (227.797 us; speedup 1.0000x reference)
//
#include <hip/hip_runtime.h>
#include <hip/hip_bf16.h>

#define BB 512
#define CC 112
#define DD 128
#define HH 8
#define HD 16
#define KK 8

typedef unsigned short u16;
typedef short short8 __attribute__((ext_vector_type(8)));
typedef float f32x4 __attribute__((ext_vector_type(4)));
typedef float f32x16 __attribute__((ext_vector_type(16)));

#define MFMA16(a, b, c) __builtin_amdgcn_mfma_f32_16x16x32_bf16(a, b, c, 0, 0, 0)
#define MFMA32(a, b, c) __builtin_amdgcn_mfma_f32_32x32x16_bf16(a, b, c, 0, 0, 0)

__device__ inline u16 f2bf(float f) {
  union { float f; unsigned u; } v{f};
  unsigned r = (v.u + 0x7FFFu + ((v.u >> 16) & 1u)) >> 16;
  return (u16)r;
}
__device__ inline float bf2f(u16 u) {
  union { unsigned u; float f; } v;
  v.u = ((unsigned)u) << 16;
  return v.f;
}
__device__ inline unsigned pk2(float a, float b) {
  __hip_bfloat162 h = __float22bfloat162_rn(float2{a, b});
  union { __hip_bfloat162 h; unsigned u; } v{h};
  return v.u;
}

// ---------------------------------------------------------------------------
// K0: convert 4x128x128 fp32 weights (wq,wk,wv,wo) -> bf16.
// ---------------------------------------------------------------------------
__global__ __launch_bounds__(256) void k_wcvt(
    const float* __restrict__ wq, const float* __restrict__ wk,
    const float* __restrict__ wv, const float* __restrict__ wo,
    u16* __restrict__ w_b) {
  const int i = (blockIdx.x * 256 + threadIdx.x);  // handles 4 floats
  const int sel = i >> 12, off = i & 4095;         // 4096 float4 per matrix
  const float* w = (sel == 0) ? wq : (sel == 1) ? wk : (sel == 2) ? wv : wo;
  const float4 v = ((const float4*)w)[off];
  ((uint2*)w_b)[i] = uint2{pk2(v.x, v.y), pk2(v.z, v.w)};
}

// ---------------------------------------------------------------------------
// K1: fused conv+GELU+BN+residual+QKV. Block=256 (4 waves), 32 token rows.
// Wave (tile,half): tile = M-tile (16 rows), half = which 4 of 8 heads.
// Two waves per M-tile duplicate the register-resident conv (cheap VALU) to
// double grid wave-parallelism: 1792 blocks x 4 waves = 7168 waves (~7/SIMD),
// breaking the 3584-wave M-tile cap that latency-bound round 6 (occ 31%).
// B-frags direct from global bf16 weights (L1). Zero LDS, zero barriers.
// GELU: tanh-form via sigma(2z) -- one __expf, max abs err ~3e-4.
// ---------------------------------------------------------------------------
__global__ __launch_bounds__(256) void k_cqkv(
    const float* __restrict__ x, const float* __restrict__ cw,
    const float* __restrict__ cb, const float* __restrict__ bg,
    const float* __restrict__ bb_, const float* __restrict__ bm,
    const float* __restrict__ bv, const u16* __restrict__ w_b,
    const float* __restrict__ bq, const float* __restrict__ bk,
    const float* __restrict__ bvv,
    u16* __restrict__ src_b, u16* __restrict__ qb, u16* __restrict__ kb,
    u16* __restrict__ vtb) {
  const int t = threadIdx.x;
  const int wave = t >> 6, lane = t & 63;
  const int quad = lane >> 4, n = lane & 15;
  const int tile = wave >> 1;   // 0..1  M-tile within block
  const int half = wave & 1;    // 0..1  head-half
  const int row0w = blockIdx.x * 32 + tile * 16;
  const int row_g = row0w + n;  // this lane's token row
  const int ch = row_g % CC;    // conv channel

  const float4 w0 = *(const float4*)(cw + ch * KK);
  const float4 w1 = *(const float4*)(cw + ch * KK + 4);
  const float cbv = cb[ch];
  const float bscale = bg[ch] * rsqrtf(bv[ch] + 1e-5f);
  const float bmv = bm[ch], bbv = bb_[ch];

  const float* __restrict__ xr = x + (size_t)row_g * DD;
  u16* __restrict__ sbr = src_b + (size_t)row_g * DD;

  short8 A[4];
#pragma unroll
  for (int kf = 0; kf < 4; ++kf) {
    const int c0 = kf * 32 + quad * 8;  // 8 outputs c0..c0+7
    float in[16];                       // cols c0-4 .. c0+11
#pragma unroll
    for (int f = 0; f < 4; ++f) {
      const int fi = (c0 >> 2) - 1 + f;
      float4 vv = {0.f, 0.f, 0.f, 0.f};
      if (fi >= 0 && fi < 32) vv = ((const float4*)xr)[fi];
      in[f * 4 + 0] = vv.x; in[f * 4 + 1] = vv.y;
      in[f * 4 + 2] = vv.z; in[f * 4 + 3] = vv.w;
    }
    u16 ob[8];
#pragma unroll
    for (int i = 0; i < 8; ++i) {
      float a = 0.f;
      a = fmaf(in[i + 1], w0.x, a);
      a = fmaf(in[i + 2], w0.y, a);
      a = fmaf(in[i + 3], w0.z, a);
      a = fmaf(in[i + 4], w0.w, a);
      a = fmaf(in[i + 5], w1.x, a);
      a = fmaf(in[i + 6], w1.y, a);
      a = fmaf(in[i + 7], w1.z, a);
      a = fmaf(in[i + 8], w1.w, a);
      a += cbv;
      // GELU tanh-form: g = a * sigma(2*0.79788456*(a + 0.044715 a^3))
      const float u = fmaf(0.044715f * a, a, 1.0f);
      const float e = __expf(a * u * -1.5957691216f);
      const float g = a * __frcp_rn(1.f + e);
      const float s = in[i + 4] + (g - bmv) * bscale + bbv;  // x + BN(GELU)
      ob[i] = f2bf(s);
    }
    A[kf] = *(short8*)ob;
    if (half == 0) *(short8*)(sbr + c0) = A[kf];  // one wave stores residual
  }

  // hoisted store bases for MFMA C-layout rows (token = row0w+quad*4+r)
  int qk_base[4], vt_base[4];
#pragma unroll
  for (int r = 0; r < 4; ++r) {
    const int g = row0w + quad * 4 + r;
    const int b_ = g / CC, c_ = g - b_ * CC;
    qk_base[r] = (b_ * (HH * CC) + c_) * HD + n;     // + h*CC*HD per head
    vt_base[r] = b_ * (HH * HD * CC) + n * CC + c_;  // + h*HD*CC per head
  }

  const float* const biases[3] = {bq, bk, bvv};
  for (int m = 0; m < 3; ++m) {
    const u16* __restrict__ wm = w_b + m * 16384;
    const float* __restrict__ bias = biases[m];
#pragma unroll
    for (int ntl = 0; ntl < 4; ++ntl) {
      const int nt = half * 4 + ntl;  // head index
      f32x4 acc = {0.f, 0.f, 0.f, 0.f};
#pragma unroll
      for (int kf = 0; kf < 4; ++kf) {
        const short8 Bf =
            *(const short8*)(wm + (nt * 16 + n) * DD + kf * 32 + quad * 8);
        acc = MFMA16(A[kf], Bf, acc);
      }
      const float bcol = bias[nt * 16 + n];
      if (m < 2) {
        u16* __restrict__ o = (m == 0) ? qb : kb;
        const int hoff = nt * (CC * HD);
#pragma unroll
        for (int r = 0; r < 4; ++r)
          o[qk_base[r] + hoff] = f2bf(acc[r] + bcol);
      } else {
        const int hoff = nt * (HD * CC);
#pragma unroll
        for (int r = 0; r < 4; ++r)
          vtb[vt_base[r] + hoff] = f2bf(acc[r] + bcol);
      }
    }
  }
}

// ---------------------------------------------------------------------------
// K2: attention, block=256 (4 waves) per (b,h); wave owns 32 queries via
// mfma_32x32x16. Scores transposed (S^T = K*Q^T) -> softmax reg-local + one
// shfl_xor(32). PV A-frags assembled in registers via one shfl_xor(32) pair.
// V^T frags direct from global. Zero LDS, zero barriers.
// ---------------------------------------------------------------------------
__global__ __launch_bounds__(256) void k_attn(
    const u16* __restrict__ qb_, const u16* __restrict__ kb_,
    const u16* __restrict__ vtb_, u16* __restrict__ ab_) {
  const int bh = blockIdx.x;  // b*HH + h
  const int b = bh >> 3, h = bh & 7;
  const int t = threadIdx.x;
  const int wave = t >> 6;  // query tile (32 queries)
  const int lane = t & 63;
  const int lo = lane & 31;
  const int hi = lane >> 5;
  const int hi8 = hi * 8;
  const u16* __restrict__ qh = qb_ + (size_t)bh * (CC * HD);
  const u16* __restrict__ kh = kb_ + (size_t)bh * (CC * HD);
  const u16* __restrict__ vth = vtb_ + (size_t)bh * (HD * CC);
  u16* __restrict__ aout = ab_ + (size_t)b * (CC * DD) + h * HD;

  const int qt0 = wave * 32;
  short8 Bq = {};
  if (qt0 + lo < CC) Bq = *(const short8*)(qh + (qt0 + lo) * HD + hi8);
  f32x16 sa[4];
#pragma unroll
  for (int mt = 0; mt < 4; ++mt) {
    short8 Ak = {};
    const int key = mt * 32 + lo;
    if (key < CC) Ak = *(const short8*)(kh + key * HD + hi8);
    f32x16 z = {};
    sa[mt] = MFMA32(Ak, Bq, z);
  }
  // lane holds S^T[key = 32*mt + (r&3)+8*(r>>2)+4*hi][query = qt0+lo];
  // valid: mt<3 all regs, mt=3 regs 0..7 (keys 96..111).
  const float C1 = 0.25f * 1.44269504088896341f;  // SCALE * log2(e)
  float mx = -1e30f;
#pragma unroll
  for (int mt = 0; mt < 4; ++mt) {
    const int rmax = (mt == 3) ? 8 : 16;
#pragma unroll
    for (int r = 0; r < 16; ++r)
      if (r < rmax) mx = fmaxf(mx, sa[mt][r]);
  }
  mx = fmaxf(mx, __shfl_xor(mx, 32));
  const float mxc = mx * C1;
  float sum = 0.f;
#pragma unroll
  for (int mt = 0; mt < 4; ++mt) {
    const int rmax = (mt == 3) ? 8 : 16;
#pragma unroll
    for (int r = 0; r < 16; ++r)
      if (r < rmax) {
        const float p = exp2f(fmaf(sa[mt][r], C1, -mxc));
        sa[mt][r] = p;
        sum += p;
      }
  }
  sum += __shfl_xor(sum, 32);
  const float rinv = 1.f / sum;
  // pack normalized P: U0/U1[mt][rq] = bf16x2 pairs of regs 4rq..4rq+3
  unsigned U0[4][4], U1[4][4];
#pragma unroll
  for (int mt = 0; mt < 4; ++mt) {
    const int rqmax = (mt == 3) ? 2 : 4;
#pragma unroll
    for (int rq = 0; rq < 4; ++rq)
      if (rq < rqmax) {
        U0[mt][rq] = pk2(sa[mt][4 * rq + 0] * rinv, sa[mt][4 * rq + 1] * rinv);
        U1[mt][rq] = pk2(sa[mt][4 * rq + 2] * rinv, sa[mt][4 * rq + 3] * rinv);
      }
  }
  // PV: O[32q][16e], 7 K-tiles of 16 keys. A-frag assembled via shfl_xor(32).
  f32x16 oacc = {};
#pragma unroll
  for (int kt = 0; kt < 7; ++kt) {
    const int mt = kt >> 1;
    const int c = 2 * (kt & 1);  // base reg-quad; own = c+hi, sent = c+(1-hi)
    const unsigned own0 = hi ? U0[mt][c + 1] : U0[mt][c];
    const unsigned own1 = hi ? U1[mt][c + 1] : U1[mt][c];
    const unsigned snd0 = hi ? U0[mt][c] : U0[mt][c + 1];
    const unsigned snd1 = hi ? U1[mt][c] : U1[mt][c + 1];
    const unsigned got0 = __shfl_xor(snd0, 32);
    const unsigned got1 = __shfl_xor(snd1, 32);
    union { unsigned u[4]; short8 s; } ap;
    ap.u[0] = hi ? got0 : own0;
    ap.u[1] = hi ? got1 : own1;
    ap.u[2] = hi ? own0 : got0;
    ap.u[3] = hi ? own1 : got1;
    short8 Bv = {};
    if (lo < HD) Bv = *(const short8*)(vth + lo * CC + kt * 16 + hi8);
    oacc = MFMA32(ap.s, Bv, oacc);
  }
  // D[row=query-in-tile][col=e=lo]; store real e / real queries
  if (lo < HD) {
#pragma unroll
    for (int r = 0; r < 16; ++r) {
      const int qrow = qt0 + (r & 3) + 8 * (r >> 2) + 4 * hi;
      if (qrow < CC) aout[(size_t)qrow * DD + lo] = f2bf(oacc[r]);
    }
  }
}

// ---------------------------------------------------------------------------
// K3: out = LN(src + attn @ Wo^T + bo). Block=256 (4 waves), 32 rows.
// Wave (tile,half): half = which 4 of 8 N-tiles -> 7168 waves (2x round 6).
// LN partial sums combined across the wave pair via 512B LDS + one barrier.
// ---------------------------------------------------------------------------
__global__ __launch_bounds__(256) void k_out(
    const u16* __restrict__ a_b, const u16* __restrict__ w_bo,
    const float* __restrict__ bo, const u16* __restrict__ src_b,
    const float* __restrict__ lg, const float* __restrict__ lb,
    float* __restrict__ out) {
  __shared__ float ls[2][2][16][2];  // [tile][half][row][{sum,sq}]
  const int t = threadIdx.x;
  const int wave = t >> 6, lane = t & 63;
  const int quad = lane >> 4, n = lane & 15;
  const int tile = wave >> 1;
  const int half = wave & 1;
  const int row0 = blockIdx.x * 32 + tile * 16;
  short8 A[4];
  {
    const size_t rbase = (size_t)(row0 + n) * DD;
#pragma unroll
    for (int kf = 0; kf < 4; ++kf)
      A[kf] = *(const short8*)(a_b + rbase + kf * 32 + quad * 8);
  }
  float v[4][4];
#pragma unroll
  for (int ntl = 0; ntl < 4; ++ntl) {
    const int nt = half * 4 + ntl;
    f32x4 acc = {0.f, 0.f, 0.f, 0.f};
#pragma unroll
    for (int kf = 0; kf < 4; ++kf) {
      const short8 Bf =
          *(const short8*)(w_bo + (nt * 16 + n) * DD + kf * 32 + quad * 8);
      acc = MFMA16(A[kf], Bf, acc);
    }
    const int col = nt * 16 + n;
    const float bcol = bo[col];
#pragma unroll
    for (int r = 0; r < 4; ++r)
      v[ntl][r] = acc[r] + bcol +
                  bf2f(src_b[(size_t)(row0 + quad * 4 + r) * DD + col]);
  }
  float sum[4] = {0.f, 0.f, 0.f, 0.f}, sq[4] = {0.f, 0.f, 0.f, 0.f};
#pragma unroll
  for (int ntl = 0; ntl < 4; ++ntl)
#pragma unroll
    for (int r = 0; r < 4; ++r) {
      sum[r] += v[ntl][r];
      sq[r] = fmaf(v[ntl][r], v[ntl][r], sq[r]);
    }
#pragma unroll
  for (int d = 1; d < 16; d <<= 1)
#pragma unroll
    for (int r = 0; r < 4; ++r) {
      sum[r] += __shfl_xor(sum[r], d);
      sq[r] += __shfl_xor(sq[r], d);
    }
  // cross-wave (half) combine via LDS
  if (n == 0) {
#pragma unroll
    for (int r = 0; r < 4; ++r) {
      ls[tile][half][quad * 4 + r][0] = sum[r];
      ls[tile][half][quad * 4 + r][1] = sq[r];
    }
  }
  __syncthreads();
  float mu[4], rs[4];
#pragma unroll
  for (int r = 0; r < 4; ++r) {
    const float fs = sum[r] + ls[tile][1 - half][quad * 4 + r][0];
    const float fq = sq[r] + ls[tile][1 - half][quad * 4 + r][1];
    mu[r] = fs * (1.f / DD);
    const float var = fq * (1.f / DD) - mu[r] * mu[r];
    rs[r] = rsqrtf(var + 1e-5f);
  }
#pragma unroll
  for (int ntl = 0; ntl < 4; ++ntl) {
    const int col = (half * 4 + ntl) * 16 + n;
    const float g = lg[col], be = lb[col];
#pragma unroll
    for (int r = 0; r < 4; ++r)
      out[(size_t)(row0 + quad * 4 + r) * DD + col] =
          (v[ntl][r] - mu[r]) * rs[r] * g + be;
  }
}

extern "C" void kernel_launch(void* const* d_in, const int* in_sizes, int n_in,
                              void* d_out, int out_size, void* d_ws,
                              size_t ws_size, hipStream_t stream) {
  (void)in_sizes; (void)n_in; (void)out_size; (void)ws_size;
  const float* x   = (const float*)d_in[0];
  const float* cw  = (const float*)d_in[1];
  const float* cb  = (const float*)d_in[2];
  const float* bg  = (const float*)d_in[3];
  const float* bb  = (const float*)d_in[4];
  const float* bm  = (const float*)d_in[5];
  const float* bv  = (const float*)d_in[6];
  const float* wq  = (const float*)d_in[7];
  const float* bq  = (const float*)d_in[8];
  const float* wk  = (const float*)d_in[9];
  const float* bk  = (const float*)d_in[10];
  const float* wv  = (const float*)d_in[11];
  const float* bvv = (const float*)d_in[12];
  const float* wo  = (const float*)d_in[13];
  const float* bo  = (const float*)d_in[14];
  const float* lg  = (const float*)d_in[15];
  const float* lb  = (const float*)d_in[16];
  float* out = (float*)d_out;

  const size_t NE = (size_t)BB * CC * DD;  // 7,340,032
  u16* ub = (u16*)d_ws;
  u16* src_b = ub;            // bf16 src, row-major [B*C, D]
  u16* q_b   = ub + NE;       // head-major [B,H,C,16]
  u16* k_b   = ub + 2 * NE;   // head-major [B,H,C,16]
  u16* vt_b  = ub + 3 * NE;   // transposed head-major [B,H,16,C]
  u16* a_b   = ub + 4 * NE;   // attention out, row-major [B*C, D]
  u16* w_b   = ub + 5 * NE;   // 4 x 128x128 bf16 weights (q,k,v,o)

  k_wcvt<<<64, 256, 0, stream>>>(wq, wk, wv, wo, w_b);
  k_cqkv<<<(BB * CC) / 32, 256, 0, stream>>>(
      x, cw, cb, bg, bb, bm, bv, w_b, bq, bk, bvv, src_b, q_b, k_b, vt_b);
  k_attn<<<BB * HH, 256, 0, stream>>>(q_b, k_b, vt_b, a_b);
  k_out<<<(BB * CC) / 32, 256, 0, stream>>>(a_b, w_b + 3 * 16384, bo, src_b,
                                            lg, lb, out);
}

// Round 8
// 172.417 us; speedup vs baseline: 1.3212x; 1.3212x over previous
//
#include <hip/hip_runtime.h>
#include <hip/hip_bf16.h>

#define BB 512
#define CC 112
#define DD 128
#define HH 8
#define HD 16
#define KK 8
// LDS row stride for 128-col bf16 tiles: 140 u16 = 70 words (≡6 mod 32),
// R3/R4-measured low-conflict for the kf*32+quad*8 frag read pattern.
#define SROW 140

typedef unsigned short u16;
typedef short short8 __attribute__((ext_vector_type(8)));
typedef float f32x4 __attribute__((ext_vector_type(4)));
typedef float f32x16 __attribute__((ext_vector_type(16)));

#define MFMA16(a, b, c) __builtin_amdgcn_mfma_f32_16x16x32_bf16(a, b, c, 0, 0, 0)
#define MFMA32(a, b, c) __builtin_amdgcn_mfma_f32_32x32x16_bf16(a, b, c, 0, 0, 0)

__device__ inline u16 f2bf(float f) {
  union { float f; unsigned u; } v{f};
  unsigned r = (v.u + 0x7FFFu + ((v.u >> 16) & 1u)) >> 16;
  return (u16)r;
}
__device__ inline float bf2f(u16 u) {
  union { unsigned u; float f; } v;
  v.u = ((unsigned)u) << 16;
  return v.f;
}
__device__ inline unsigned pk2(float a, float b) {
  __hip_bfloat162 h = __float22bfloat162_rn(float2{a, b});
  union { __hip_bfloat162 h; unsigned u; } v{h};
  return v.u;
}

// ---------------------------------------------------------------------------
// K0: convert 4x128x128 fp32 weights (wq,wk,wv,wo) -> bf16.
// ---------------------------------------------------------------------------
__global__ __launch_bounds__(256) void k_wcvt(
    const float* __restrict__ wq, const float* __restrict__ wk,
    const float* __restrict__ wv, const float* __restrict__ wo,
    u16* __restrict__ w_b) {
  const int i = (blockIdx.x * 256 + threadIdx.x);  // handles 4 floats
  const int sel = i >> 12, off = i & 4095;
  const float* w = (sel == 0) ? wq : (sel == 1) ? wk : (sel == 2) ? wv : wo;
  const float4 v = ((const float4*)w)[off];
  ((uint2*)w_b)[i] = uint2{pk2(v.x, v.y), pk2(v.z, v.w)};
}

// ---------------------------------------------------------------------------
// K1: one block per batch b (512 blocks x 512 threads = 8 waves).
// Phase 1 (conv): 4 threads/row x 112 rows compute conv+GELU+BN+residual once
// into LDS S[112][SROW] (and bf16 src_b to global for the k_attno residual).
// Phase 2 (QKV): wave w = head w; 12 weight B-frags held in REGISTERS (loaded
// once, amortized over 7 M-tiles); A-frags from LDS; 12 MFMA/tile (A reused
// 3x). q/k head-major [B,H,C,16]; v transposed [B,H,16,C]. One barrier total.
// ---------------------------------------------------------------------------
__global__ __launch_bounds__(512, 4) void k_cqkv(
    const float* __restrict__ x, const float* __restrict__ cw,
    const float* __restrict__ cb, const float* __restrict__ bg,
    const float* __restrict__ bb_, const float* __restrict__ bm,
    const float* __restrict__ bv, const u16* __restrict__ w_b,
    const float* __restrict__ bq, const float* __restrict__ bk,
    const float* __restrict__ bvv,
    u16* __restrict__ src_b, u16* __restrict__ qb, u16* __restrict__ kb,
    u16* __restrict__ vtb) {
  __shared__ u16 S[CC * SROW];
  const int b = blockIdx.x;
  const int t = threadIdx.x;

  // ---- conv phase: thread (tg,sub) -> row tg, cols sub*32..sub*32+31 ----
  const int tg = t >> 2, sub = t & 3;
  if (tg < CC) {
    const int row = tg, ch = tg;  // row within batch == conv channel
    const float4 w0 = *(const float4*)(cw + ch * KK);
    const float4 w1 = *(const float4*)(cw + ch * KK + 4);
    const float cbv = cb[ch];
    const float bscale = bg[ch] * rsqrtf(bv[ch] + 1e-5f);
    const float bmv = bm[ch], bbv = bb_[ch];
    const float* __restrict__ xr = x + ((size_t)b * CC + row) * DD;
    float in[40];  // cols sub*32-4 .. sub*32+35
#pragma unroll
    for (int f = 0; f < 10; ++f) {
      const int fi = 8 * sub - 1 + f;
      float4 vv = {0.f, 0.f, 0.f, 0.f};
      if (fi >= 0 && fi < 32) vv = ((const float4*)xr)[fi];
      in[f * 4 + 0] = vv.x; in[f * 4 + 1] = vv.y;
      in[f * 4 + 2] = vv.z; in[f * 4 + 3] = vv.w;
    }
    unsigned pkv[16];
#pragma unroll
    for (int i2 = 0; i2 < 16; ++i2) {
      float oo[2];
#pragma unroll
      for (int j = 0; j < 2; ++j) {
        const int i = i2 * 2 + j;
        float a = 0.f;
        a = fmaf(in[i + 1], w0.x, a);
        a = fmaf(in[i + 2], w0.y, a);
        a = fmaf(in[i + 3], w0.z, a);
        a = fmaf(in[i + 4], w0.w, a);
        a = fmaf(in[i + 5], w1.x, a);
        a = fmaf(in[i + 6], w1.y, a);
        a = fmaf(in[i + 7], w1.z, a);
        a = fmaf(in[i + 8], w1.w, a);
        a += cbv;
        // GELU tanh-form via sigma (validated R7, absmax unchanged)
        const float u = fmaf(0.044715f * a, a, 1.0f);
        const float e = __expf(a * u * -1.5957691216f);
        const float g = a * __frcp_rn(1.f + e);
        oo[j] = in[i + 4] + (g - bmv) * bscale + bbv;  // x + BN(GELU)
      }
      pkv[i2] = pk2(oo[0], oo[1]);
    }
    u16* srow = S + row * SROW + sub * 32;
#pragma unroll
    for (int k2 = 0; k2 < 8; ++k2)
      *(uint2*)(srow + k2 * 4) = ((uint2*)pkv)[k2];  // 8B-aligned LDS writes
    uint4* gsr = (uint4*)(src_b + ((size_t)b * CC + row) * DD + sub * 32);
#pragma unroll
    for (int k4 = 0; k4 < 4; ++k4) gsr[k4] = ((uint4*)pkv)[k4];
  }
  __syncthreads();

  // ---- QKV phase: wave = head ----
  const int wave = t >> 6, lane = t & 63;
  const int quad = lane >> 4, n = lane & 15;
  const int h = wave;
  short8 Bf0[4], Bf1[4], Bf2[4];  // q/k/v weight frags, register-resident
#pragma unroll
  for (int kf = 0; kf < 4; ++kf) {
    const int wi = (h * 16 + n) * DD + kf * 32 + quad * 8;
    Bf0[kf] = *(const short8*)(w_b + wi);
    Bf1[kf] = *(const short8*)(w_b + 16384 + wi);
    Bf2[kf] = *(const short8*)(w_b + 32768 + wi);
  }
  const float bqv = bq[h * 16 + n];
  const float bkv = bk[h * 16 + n];
  const float bvv2 = bvv[h * 16 + n];
  u16* __restrict__ qhp = qb + (size_t)(b * HH + h) * CC * HD;
  u16* __restrict__ khp = kb + (size_t)(b * HH + h) * CC * HD;
  u16* __restrict__ vhp = vtb + (size_t)(b * HH + h) * HD * CC;
#pragma unroll
  for (int mt = 0; mt < 7; ++mt) {
    short8 A[4];
#pragma unroll
    for (int kf = 0; kf < 4; ++kf)
      A[kf] = *(const short8*)&S[(mt * 16 + n) * SROW + kf * 32 + quad * 8];
    f32x4 aq = {0.f, 0.f, 0.f, 0.f};
    f32x4 ak = {0.f, 0.f, 0.f, 0.f};
    f32x4 av = {0.f, 0.f, 0.f, 0.f};
#pragma unroll
    for (int kf = 0; kf < 4; ++kf) {
      aq = MFMA16(A[kf], Bf0[kf], aq);
      ak = MFMA16(A[kf], Bf1[kf], ak);
      av = MFMA16(A[kf], Bf2[kf], av);
    }
#pragma unroll
    for (int r = 0; r < 4; ++r) {
      const int row = mt * 16 + quad * 4 + r;
      qhp[row * HD + n] = f2bf(aq[r] + bqv);
      khp[row * HD + n] = f2bf(ak[r] + bkv);
      vhp[n * CC + row] = f2bf(av[r] + bvv2);
    }
  }
}

// ---------------------------------------------------------------------------
// K2: one block per batch b (512 blocks x 512 threads). Phase 1: wave w =
// head w runs full attention (R6-verified transposed-score core, frags from
// global, P kept in registers via shfl_xor(32)), O written to LDS AO[c][128].
// Barrier. Phase 2: waves 0..6 do out-proj M-tile w (A-frags from AO, Wo from
// global bf16) + bias + residual(src_b) + LayerNorm -> fp32 out.
// ---------------------------------------------------------------------------
__global__ __launch_bounds__(512, 4) void k_attno(
    const u16* __restrict__ qb_, const u16* __restrict__ kb_,
    const u16* __restrict__ vtb_, const u16* __restrict__ w_bo,
    const float* __restrict__ bo, const u16* __restrict__ src_b,
    const float* __restrict__ lg, const float* __restrict__ lb,
    float* __restrict__ out) {
  __shared__ u16 AO[CC * SROW];
  const int b = blockIdx.x;
  const int t = threadIdx.x;
  const int wave = t >> 6, lane = t & 63;

  // ---- attention phase: wave = head ----
  {
    const int h = wave;
    const int lo = lane & 31, hi = lane >> 5, hi8 = hi * 8;
    const u16* __restrict__ qh = qb_ + (size_t)(b * HH + h) * CC * HD;
    const u16* __restrict__ kh = kb_ + (size_t)(b * HH + h) * CC * HD;
    const u16* __restrict__ vth = vtb_ + (size_t)(b * HH + h) * HD * CC;
    for (int qt = 0; qt < 4; ++qt) {
      const int qt0 = qt * 32;
      short8 Bq = {};
      if (qt0 + lo < CC) Bq = *(const short8*)(qh + (qt0 + lo) * HD + hi8);
      f32x16 sa[4];
#pragma unroll
      for (int mt = 0; mt < 4; ++mt) {
        short8 Ak = {};
        const int key = mt * 32 + lo;
        if (key < CC) Ak = *(const short8*)(kh + key * HD + hi8);
        f32x16 z = {};
        sa[mt] = MFMA32(Ak, Bq, z);
      }
      // lane holds S^T[key=32mt+(r&3)+8(r>>2)+4hi][query=qt0+lo];
      // valid: mt<3 all regs, mt=3 regs 0..7 (keys 96..111).
      const float C1 = 0.25f * 1.44269504088896341f;  // SCALE * log2(e)
      float mx = -1e30f;
#pragma unroll
      for (int mt = 0; mt < 4; ++mt) {
        const int rmax = (mt == 3) ? 8 : 16;
#pragma unroll
        for (int r = 0; r < 16; ++r)
          if (r < rmax) mx = fmaxf(mx, sa[mt][r]);
      }
      mx = fmaxf(mx, __shfl_xor(mx, 32));
      const float mxc = mx * C1;
      float sum = 0.f;
#pragma unroll
      for (int mt = 0; mt < 4; ++mt) {
        const int rmax = (mt == 3) ? 8 : 16;
#pragma unroll
        for (int r = 0; r < 16; ++r)
          if (r < rmax) {
            const float p = exp2f(fmaf(sa[mt][r], C1, -mxc));
            sa[mt][r] = p;
            sum += p;
          }
      }
      sum += __shfl_xor(sum, 32);
      const float rinv = 1.f / sum;
      unsigned U0[4][4], U1[4][4];
#pragma unroll
      for (int mt = 0; mt < 4; ++mt) {
        const int rqmax = (mt == 3) ? 2 : 4;
#pragma unroll
        for (int rq = 0; rq < 4; ++rq)
          if (rq < rqmax) {
            U0[mt][rq] =
                pk2(sa[mt][4 * rq + 0] * rinv, sa[mt][4 * rq + 1] * rinv);
            U1[mt][rq] =
                pk2(sa[mt][4 * rq + 2] * rinv, sa[mt][4 * rq + 3] * rinv);
          }
      }
      f32x16 oacc = {};
#pragma unroll
      for (int kt = 0; kt < 7; ++kt) {
        const int mt = kt >> 1;
        const int c = 2 * (kt & 1);
        const unsigned own0 = hi ? U0[mt][c + 1] : U0[mt][c];
        const unsigned own1 = hi ? U1[mt][c + 1] : U1[mt][c];
        const unsigned snd0 = hi ? U0[mt][c] : U0[mt][c + 1];
        const unsigned snd1 = hi ? U1[mt][c] : U1[mt][c + 1];
        const unsigned got0 = __shfl_xor(snd0, 32);
        const unsigned got1 = __shfl_xor(snd1, 32);
        union { unsigned u[4]; short8 s; } ap;
        ap.u[0] = hi ? got0 : own0;
        ap.u[1] = hi ? got1 : own1;
        ap.u[2] = hi ? own0 : got0;
        ap.u[3] = hi ? own1 : got1;
        short8 Bv = {};
        if (lo < HD) Bv = *(const short8*)(vth + lo * CC + kt * 16 + hi8);
        oacc = MFMA32(ap.s, Bv, oacc);
      }
      if (lo < HD) {
#pragma unroll
        for (int r = 0; r < 16; ++r) {
          const int qrow = qt0 + (r & 3) + 8 * (r >> 2) + 4 * hi;
          if (qrow < CC) AO[qrow * SROW + h * HD + lo] = f2bf(oacc[r]);
        }
      }
    }
  }
  __syncthreads();

  // ---- out-proj + LN phase: waves 0..6, M-tile = wave ----
  if (wave < 7) {
    const int quad = lane >> 4, n = lane & 15;
    const int mt = wave;
    short8 A[4];
#pragma unroll
    for (int kf = 0; kf < 4; ++kf)
      A[kf] = *(const short8*)&AO[(mt * 16 + n) * SROW + kf * 32 + quad * 8];
    float v[8][4];
#pragma unroll
    for (int nt = 0; nt < 8; ++nt) {
      f32x4 acc = {0.f, 0.f, 0.f, 0.f};
#pragma unroll
      for (int kf = 0; kf < 4; ++kf) {
        const short8 Bf =
            *(const short8*)(w_bo + (nt * 16 + n) * DD + kf * 32 + quad * 8);
        acc = MFMA16(A[kf], Bf, acc);
      }
      const int col = nt * 16 + n;
      const float bcol = bo[col];
#pragma unroll
      for (int r = 0; r < 4; ++r)
        v[nt][r] =
            acc[r] + bcol +
            bf2f(src_b[((size_t)b * CC + mt * 16 + quad * 4 + r) * DD + col]);
    }
    float sum[4] = {0.f, 0.f, 0.f, 0.f}, sq[4] = {0.f, 0.f, 0.f, 0.f};
#pragma unroll
    for (int nt = 0; nt < 8; ++nt)
#pragma unroll
      for (int r = 0; r < 4; ++r) {
        sum[r] += v[nt][r];
        sq[r] = fmaf(v[nt][r], v[nt][r], sq[r]);
      }
#pragma unroll
    for (int d = 1; d < 16; d <<= 1)
#pragma unroll
      for (int r = 0; r < 4; ++r) {
        sum[r] += __shfl_xor(sum[r], d);
        sq[r] += __shfl_xor(sq[r], d);
      }
    float mu[4], rs[4];
#pragma unroll
    for (int r = 0; r < 4; ++r) {
      mu[r] = sum[r] * (1.f / DD);
      const float var = sq[r] * (1.f / DD) - mu[r] * mu[r];
      rs[r] = rsqrtf(var + 1e-5f);
    }
#pragma unroll
    for (int nt = 0; nt < 8; ++nt) {
      const int col = nt * 16 + n;
      const float g = lg[col], be = lb[col];
#pragma unroll
      for (int r = 0; r < 4; ++r)
        out[((size_t)b * CC + mt * 16 + quad * 4 + r) * DD + col] =
            (v[nt][r] - mu[r]) * rs[r] * g + be;
    }
  }
}

extern "C" void kernel_launch(void* const* d_in, const int* in_sizes, int n_in,
                              void* d_out, int out_size, void* d_ws,
                              size_t ws_size, hipStream_t stream) {
  (void)in_sizes; (void)n_in; (void)out_size; (void)ws_size;
  const float* x   = (const float*)d_in[0];
  const float* cw  = (const float*)d_in[1];
  const float* cb  = (const float*)d_in[2];
  const float* bg  = (const float*)d_in[3];
  const float* bb  = (const float*)d_in[4];
  const float* bm  = (const float*)d_in[5];
  const float* bv  = (const float*)d_in[6];
  const float* wq  = (const float*)d_in[7];
  const float* bq  = (const float*)d_in[8];
  const float* wk  = (const float*)d_in[9];
  const float* bk  = (const float*)d_in[10];
  const float* wv  = (const float*)d_in[11];
  const float* bvv = (const float*)d_in[12];
  const float* wo  = (const float*)d_in[13];
  const float* bo  = (const float*)d_in[14];
  const float* lg  = (const float*)d_in[15];
  const float* lb  = (const float*)d_in[16];
  float* out = (float*)d_out;

  const size_t NE = (size_t)BB * CC * DD;  // 7,340,032
  u16* ub = (u16*)d_ws;
  u16* src_b = ub;            // bf16 src, row-major [B*C, D]
  u16* q_b   = ub + NE;       // head-major [B,H,C,16]
  u16* k_b   = ub + 2 * NE;   // head-major [B,H,C,16]
  u16* vt_b  = ub + 3 * NE;   // transposed head-major [B,H,16,C]
  u16* w_b   = ub + 4 * NE;   // 4 x 128x128 bf16 weights (q,k,v,o)

  k_wcvt<<<64, 256, 0, stream>>>(wq, wk, wv, wo, w_b);
  k_cqkv<<<BB, 512, 0, stream>>>(x, cw, cb, bg, bb, bm, bv, w_b, bq, bk, bvv,
                                 src_b, q_b, k_b, vt_b);
  k_attno<<<BB, 512, 0, stream>>>(q_b, k_b, vt_b, w_b + 3 * 16384, bo, src_b,
                                  lg, lb, out);
}